// Round 7
// baseline (78.903 us; speedup 1.0000x reference)
//
#include <hip/hip_runtime.h>
#include <hip/hip_bf16.h>
#include <math.h>

typedef unsigned short u16;
typedef unsigned int   u32;
typedef __attribute__((ext_vector_type(8)))  short bf16x8_t;
typedef __attribute__((ext_vector_type(4)))  float f32x4_t;
typedef __attribute__((ext_vector_type(16))) float f32x16_t;
typedef __attribute__((ext_vector_type(4)))  int   i32x4_t;
typedef __attribute__((ext_vector_type(2)))  u32   u32x2_t;

#define SEQ 4096
#define EMB 512
#define HD  64
#define NBATCH 4
// 1/sqrt(512) * log2(e)  (bug-faithful d_k = embed dim 512)
#define C2 0.063758718f

#define NPAIR 136                    // (g,c) pairs per batch: sum_{g=0..15}(g+1)
#define SLOTS (NBATCH * NPAIR * 8)   // 4352 wave-partial slots

__device__ __forceinline__ u16 to_bf(float f) {
    __hip_bfloat16 h = __float2bfloat16(f);
    return __builtin_bit_cast(u16, h);
}

__device__ __forceinline__ void stage16(const void* g, void* l) {
    __builtin_amdgcn_global_load_lds(
        (const __attribute__((address_space(1))) void*)g,
        (__attribute__((address_space(3))) void*)l, 16, 0, 0);
}

// ---------------------------------------------------------------------------
// Projection v3 (m97-style): A-stream via global_load_lds f32 tiles,
// triple-buffered, 2 tiles in flight, counted vmcnt (never 0 mid-loop).
// Wave-private row bands -> ZERO barriers in the k-loop. A chunks are
// XOR-swizzled (inverse-swz source + swz read, same involution) so the
// strided fragment ds_reads are conflict-free. W converted once to padded
// bf16 LDS (one barrier). 768 blocks = 3 uniform rounds at 1 block/CU.
// z: 0 -> Q, 1 -> K, 2 -> V (V written transposed [B][64][S])
// ---------------------------------------------------------------------------
__global__ __launch_bounds__(256)
void proj_kernel(const float* __restrict__ q_in, const float* __restrict__ k_in,
                 const float* __restrict__ v_in,
                 const float* __restrict__ Wq, const float* __restrict__ bq,
                 const float* __restrict__ Wk, const float* __restrict__ bk,
                 const float* __restrict__ Wv, const float* __restrict__ bv,
                 u16* __restrict__ outQ, u16* __restrict__ outK,
                 u16* __restrict__ outVT)
{
    const int z = blockIdx.y;
    const float* in   = (z == 0) ? q_in : (z == 1) ? k_in : v_in;
    const float* W    = (z == 0) ? Wq   : (z == 1) ? Wk   : Wv;
    const float* bias = (z == 0) ? bq   : (z == 1) ? bk   : bv;

    __shared__ __align__(16) u16   W_lds[64][520];      // bf16, +8 pad (2-way = free)
    __shared__ __align__(16) float A_lds[3][64][64];    // f32 tiles, chunk-swizzled

    const int tid  = threadIdx.x;
    const int lane = tid & 63;
    const int w    = tid >> 6;
    const int l15  = lane & 15;
    const int lg   = lane >> 4;
    const int g0   = blockIdx.x * 64;

    // bias: load FIRST and force completion, so loop vmcnt counts only staging
    float bvals[4];
    #pragma unroll
    for (int kn = 0; kn < 4; ++kn) bvals[kn] = bias[kn * 16 + l15];
    asm volatile("" :: "v"(bvals[0]), "v"(bvals[1]), "v"(bvals[2]), "v"(bvals[3]));

    // ---- stage W once (f32 -> bf16, padded rows) ----
    {
        const int row = tid >> 2;
        const int cb  = (tid & 3) * 128;
        const float* src = W + (size_t)row * EMB + cb;
        #pragma unroll
        for (int u = 0; u < 16; ++u) {
            f32x4_t f0 = *reinterpret_cast<const f32x4_t*>(src + 8 * u);
            f32x4_t f1 = *reinterpret_cast<const f32x4_t*>(src + 8 * u + 4);
            u16 tmp[8];
            #pragma unroll
            for (int e = 0; e < 4; ++e) { tmp[e] = to_bf(f0[e]); tmp[4 + e] = to_bf(f1[e]); }
            *reinterpret_cast<i32x4_t*>(&W_lds[row][cb + 8 * u]) =
                *reinterpret_cast<const i32x4_t*>(tmp);
        }
    }
    __syncthreads();   // W ready; also drains all vmcnt/lgkmcnt

    // ---- A staging: wave w owns rows [w*16, w*16+16) of the 64-row tile ----
    // LDS dest is wave-uniform base + lane*16 (HW); slot (r, c=lane&15) gets
    // global chunk c ^ (r&7)  (involution; read applies the same XOR).
    auto STAGE_A = [&](int buf, int t) {
        #pragma unroll
        for (int i = 0; i < 4; ++i) {
            const int rl = w * 16 + i * 4 + (lane >> 4);         // local row
            const int cs = (lane & 15) ^ (rl & 7);               // src chunk
            stage16(in + (size_t)(g0 + rl) * EMB + t * 64 + cs * 4,
                    &A_lds[buf][w * 16 + i * 4][0]);
        }
    };

    f32x4_t acc[4];
    #pragma unroll
    for (int i = 0; i < 4; ++i)
        #pragma unroll
        for (int j = 0; j < 4; ++j) acc[i][j] = 0.f;

    const int rswz = l15 & 7;

    STAGE_A(0, 0);
    STAGE_A(1, 1);

    #pragma unroll
    for (int kt = 0; kt < 8; ++kt) {
        const int buf = kt % 3;
        if (kt < 6) STAGE_A((kt + 2) % 3, kt + 2);
        // counted wait: 2 tiles (8 instrs) stay in flight; drain only at tail
        if (kt < 6)      asm volatile("s_waitcnt vmcnt(8)" ::: "memory");
        else if (kt == 6) asm volatile("s_waitcnt vmcnt(4)" ::: "memory");
        else              asm volatile("s_waitcnt vmcnt(0)" ::: "memory");
        __builtin_amdgcn_sched_barrier(0);

        #pragma unroll
        for (int ks = 0; ks < 2; ++ks) {
            const int c0 = ks * 8 + lg * 2;
            f32x4_t a0 = *reinterpret_cast<const f32x4_t*>(
                &A_lds[buf][w * 16 + l15][((c0)     ^ rswz) * 4]);
            f32x4_t a1 = *reinterpret_cast<const f32x4_t*>(
                &A_lds[buf][w * 16 + l15][((c0 + 1) ^ rswz) * 4]);
            u16 ta[8];
            #pragma unroll
            for (int e = 0; e < 4; ++e) { ta[e] = to_bf(a0[e]); ta[4 + e] = to_bf(a1[e]); }
            bf16x8_t af = *reinterpret_cast<const bf16x8_t*>(ta);
            #pragma unroll
            for (int kn = 0; kn < 4; ++kn) {
                bf16x8_t bfrag = *reinterpret_cast<const bf16x8_t*>(
                    &W_lds[kn * 16 + l15][kt * 64 + ks * 32 + 8 * lg]);
                acc[kn] = __builtin_amdgcn_mfma_f32_16x16x32_bf16(af, bfrag, acc[kn], 0, 0, 0);
            }
        }
    }

    // epilogue: bias add, bf16 store
    #pragma unroll
    for (int kn = 0; kn < 4; ++kn) {
        const int col = kn * 16 + l15;
        #pragma unroll
        for (int j = 0; j < 4; ++j) {
            const int grow = g0 + w * 16 + lg * 4 + j;
            const u16 val = to_bf(acc[kn][j] + bvals[kn]);
            if (z == 0) {
                outQ[(size_t)grow * HD + col] = val;
            } else if (z == 1) {
                outK[(size_t)grow * HD + col] = val;
            } else {
                const int b = grow >> 12, s = grow & (SEQ - 1);
                outVT[((size_t)(b * HD + col)) * SEQ + s] = val;
            }
        }
    }
}

// ---------------------------------------------------------------------------
// 8-wave flash attention (m214-style), split-K partials. (unchanged from R5)
// ---------------------------------------------------------------------------
__global__ __launch_bounds__(512, 4)
void attn8_kernel(const u16* __restrict__ Q, const u16* __restrict__ K,
                  const u16* __restrict__ VT,
                  u16* __restrict__ partO, float* __restrict__ partL)
{
    __shared__ u16 Kt[2][64 * 64];   // [buf][key*64 + h], chunk-swizzled
    __shared__ u16 Vt[2][64 * 64];   // [buf][d*64 + key], chunk-swizzled
    __shared__ u16 Pt[8][32 * 64];   // per-wave P^T [q][key], swizzled

    const int tid  = threadIdx.x;
    const int w    = tid >> 6;
    const int lane = tid & 63;
    const int q31  = lane & 31;
    const int half = lane >> 5;

    const int b = blockIdx.y;
    const int y = blockIdx.x;                 // 0..135
    int g = 0;
    while ((g + 1) * (g + 2) / 2 <= y) ++g;
    const int c = y - g * (g + 1) / 2;        // chunk 0..g

    const int R0   = 256 * g + 32 * w;        // wave's first q row
    const int q_g  = R0 + q31;                // this lane's q row
    const int nt_w = 4 * g + (w >> 1) + 1;    // key tiles this wave needs
    const int t0   = 4 * c, t1 = 4 * c + 4;   // block-wide staged tile range

    const u16* Kb  = K  + (size_t)b * SEQ * HD;
    const u16* VTb = VT + (size_t)b * HD * SEQ;

    const int srow = w * 8 + (lane >> 3);            // row within 64-row tile
    const int schk = (lane & 7) ^ ((lane >> 3) & 7); // pre-swizzled src chunk

    bf16x8_t qf0, qf1, qf2, qf3;
    {
        const u16* qp = Q + ((size_t)b * SEQ + q_g) * HD + 8 * half;
        qf0 = *(const bf16x8_t*)(qp + 0);
        qf1 = *(const bf16x8_t*)(qp + 16);
        qf2 = *(const bf16x8_t*)(qp + 32);
        qf3 = *(const bf16x8_t*)(qp + 48);
    }

    f32x16_t acc0, acc1;
    #pragma unroll
    for (int i = 0; i < 16; ++i) { acc0[i] = 0.f; acc1[i] = 0.f; }
    float lsum = 0.f;

    auto STAGE = [&](int u, int t) {
        stage16(&Kb[((size_t)(t * 64 + srow)) * HD + schk * 8], &Kt[u][w * 512]);
        stage16(&VTb[(size_t)srow * SEQ + t * 64 + schk * 8],   &Vt[u][w * 512]);
    };

    STAGE(0, t0);
    asm volatile("s_waitcnt vmcnt(0)" ::: "memory");
    __syncthreads();

    for (int t = t0; t < t1; ++t) {
        const int u = (t - t0) & 1;
        if (t + 1 < t1) STAGE(u ^ 1, t + 1);
        if (t < nt_w) {
            const bool last = (t == nt_w - 1);
            #pragma unroll
            for (int ksub = 0; ksub < 2; ++ksub) {
                f32x16_t sf;
                #pragma unroll
                for (int i = 0; i < 16; ++i) sf[i] = 0.f;
                const int kl = ksub * 32 + q31;
                #pragma unroll
                for (int s = 0; s < 4; ++s) {
                    bf16x8_t a = *(const bf16x8_t*)
                        &Kt[u][kl * 64 + ((s * 16 + 8 * half) ^ ((kl & 7) << 3))];
                    bf16x8_t qq = (s == 0) ? qf0 : (s == 1) ? qf1 : (s == 2) ? qf2 : qf3;
                    sf = __builtin_amdgcn_mfma_f32_32x32x16_bf16(a, qq, sf, 0, 0, 0);
                }
                #pragma unroll
                for (int j = 0; j < 4; ++j) {
                    float p[4];
                    #pragma unroll
                    for (int e = 0; e < 4; ++e) {
                        const int kk    = 8 * j + 4 * half + e;
                        const int key_g = t * 64 + ksub * 32 + kk;
                        float v = exp2f(sf[4 * j + e] * C2);
                        if (last && key_g > q_g) v = 0.f;
                        lsum += v;
                        p[e] = v;
                    }
                    u32x2_t pk;
                    pk[0] = (u32)to_bf(p[0]) | ((u32)to_bf(p[1]) << 16);
                    pk[1] = (u32)to_bf(p[2]) | ((u32)to_bf(p[3]) << 16);
                    const int col = (ksub * 32 + 8 * j + 4 * half) ^ ((q31 & 7) << 3);
                    *(u32x2_t*)&Pt[w][q31 * 64 + col] = pk;
                }
            }
            asm volatile("s_waitcnt lgkmcnt(0)" ::: "memory");
            __builtin_amdgcn_sched_barrier(0);
            #pragma unroll
            for (int kp = 0; kp < 4; ++kp) {
                bf16x8_t pb = *(const bf16x8_t*)
                    &Pt[w][q31 * 64 + ((kp * 16 + 8 * half) ^ ((q31 & 7) << 3))];
                {
                    const int dl = q31;
                    bf16x8_t va = *(const bf16x8_t*)
                        &Vt[u][dl * 64 + ((kp * 16 + 8 * half) ^ ((dl & 7) << 3))];
                    acc0 = __builtin_amdgcn_mfma_f32_32x32x16_bf16(va, pb, acc0, 0, 0, 0);
                }
                {
                    const int dl = 32 + q31;
                    bf16x8_t va = *(const bf16x8_t*)
                        &Vt[u][dl * 64 + ((kp * 16 + 8 * half) ^ ((dl & 7) << 3))];
                    acc1 = __builtin_amdgcn_mfma_f32_32x32x16_bf16(va, pb, acc1, 0, 0, 0);
                }
            }
        }
        asm volatile("s_waitcnt vmcnt(0)" ::: "memory");
        __syncthreads();
    }

    lsum += __shfl_xor(lsum, 32);
    const int slot = (b * NPAIR + y) * 8 + w;
    u16* po = partO + (size_t)slot * 2048;
    #pragma unroll
    for (int dsub = 0; dsub < 2; ++dsub) {
        #pragma unroll
        for (int j = 0; j < 4; ++j) {
            const f32x16_t& a = dsub ? acc1 : acc0;
            u32x2_t pk;
            pk[0] = (u32)to_bf(a[4 * j + 0]) | ((u32)to_bf(a[4 * j + 1]) << 16);
            pk[1] = (u32)to_bf(a[4 * j + 2]) | ((u32)to_bf(a[4 * j + 3]) << 16);
            const int d = 32 * dsub + 8 * j + 4 * half;
            *(u32x2_t*)&po[q31 * 64 + d] = pk;
        }
    }
    if (half == 0) partL[(size_t)slot * 32 + q31] = lsum;
}

// ---------------------------------------------------------------------------
// Reduce: sum bf16 O partials + lsum over chunks, divide, write f32 out.
// ---------------------------------------------------------------------------
__global__ __launch_bounds__(256)
void reduce8_kernel(const u16* __restrict__ partO, const float* __restrict__ partL,
                    float* __restrict__ out)
{
    const int x  = blockIdx.x;          // 0..511
    const int b  = x >> 7;
    const int gw = x & 127;
    const int g  = gw >> 3;
    const int w  = gw & 7;
    const int ybase = g * (g + 1) / 2;

    const int t  = threadIdx.x;
    const int q  = t >> 3;              // 0..31
    const int d0 = (t & 7) * 8;         // 0,8,..,56

    float acc[8];
    #pragma unroll
    for (int i = 0; i < 8; ++i) acc[i] = 0.f;
    float l = 0.f;

    for (int c = 0; c <= g; ++c) {
        const int slot = (b * NPAIR + ybase + c) * 8 + w;
        i32x4_t raw = *(const i32x4_t*)(partO + (size_t)slot * 2048 + q * 64 + d0);
        const u16* pr = (const u16*)&raw;
        #pragma unroll
        for (int i = 0; i < 8; ++i) {
            u32 bits = ((u32)pr[i]) << 16;
            acc[i] += __builtin_bit_cast(float, bits);
        }
        l += partL[(size_t)slot * 32 + q];
    }
    const float inv = 1.f / l;
    f32x4_t r0, r1;
    #pragma unroll
    for (int i = 0; i < 4; ++i) { r0[i] = acc[i] * inv; r1[i] = acc[4 + i] * inv; }
    const size_t row = (size_t)b * SEQ + g * 256 + w * 32 + q;
    *(f32x4_t*)&out[row * HD + d0]     = r0;
    *(f32x4_t*)&out[row * HD + d0 + 4] = r1;
}

extern "C" void kernel_launch(void* const* d_in, const int* in_sizes, int n_in,
                              void* d_out, int out_size, void* d_ws, size_t ws_size,
                              hipStream_t stream)
{
    const float* q_in = (const float*)d_in[0];
    const float* k_in = (const float*)d_in[1];
    const float* v_in = (const float*)d_in[2];
    const float* Wq   = (const float*)d_in[3];
    const float* bq   = (const float*)d_in[4];
    const float* Wk   = (const float*)d_in[5];
    const float* bk   = (const float*)d_in[6];
    const float* Wv   = (const float*)d_in[7];
    const float* bv   = (const float*)d_in[8];
    float* out = (float*)d_out;

    const size_t NQ = (size_t)NBATCH * SEQ * HD;     // 1,048,576 elems
    u16* wsQ   = (u16*)d_ws;
    u16* wsK   = wsQ + NQ;
    u16* wsVT  = wsK + NQ;
    u16* partO = wsVT + NQ;                          // SLOTS*2048 u16 = 17.8 MB
    float* partL = (float*)(partO + (size_t)SLOTS * 2048);  // SLOTS*32 f32

    proj_kernel<<<dim3(256, 3), 256, 0, stream>>>(q_in, k_in, v_in, Wq, bq, Wk, bk,
                                                  Wv, bv, wsQ, wsK, wsVT);
    attn8_kernel<<<dim3(NPAIR, NBATCH), 512, 0, stream>>>(wsQ, wsK, wsVT, partO, partL);
    reduce8_kernel<<<dim3(512), 256, 0, stream>>>(partO, partL, out);
}

// Round 8
// 72.048 us; speedup vs baseline: 1.0951x; 1.0951x over previous
//
#include <hip/hip_runtime.h>
#include <hip/hip_bf16.h>
#include <math.h>

typedef unsigned short u16;
typedef unsigned int   u32;
typedef __attribute__((ext_vector_type(8)))  short bf16x8_t;
typedef __attribute__((ext_vector_type(4)))  float f32x4_t;
typedef __attribute__((ext_vector_type(16))) float f32x16_t;
typedef __attribute__((ext_vector_type(4)))  int   i32x4_t;
typedef __attribute__((ext_vector_type(2)))  u32   u32x2_t;

#define SEQ 4096
#define EMB 512
#define HD  64
#define NBATCH 4
// 1/sqrt(512) * log2(e)  (bug-faithful d_k = embed dim 512)
#define C2 0.063758718f

#define NPAIR 136                    // (g,c) pairs per batch: sum_{g=0..15}(g+1)
#define SLOTS (NBATCH * NPAIR * 8)   // 4352 wave-partial slots

__device__ __forceinline__ u16 to_bf(float f) {
    __hip_bfloat16 h = __float2bfloat16(f);
    return __builtin_bit_cast(u16, h);
}

__device__ __forceinline__ void stage16(const void* g, void* l) {
    __builtin_amdgcn_global_load_lds(
        (const __attribute__((address_space(1))) void*)g,
        (__attribute__((address_space(3))) void*)l, 16, 0, 0);
}

// ---------------------------------------------------------------------------
// W prep: convert W (f32 [64][512]) to bf16 in MFMA-B-fragment order:
// wbf[((z*16+kt)*4+kn)*512 + lane*8 + e] = W_z[kn*16+(lane&15)][kt*32+(lane>>4)*8+e]
// One block per (z,kt); thread = (kn, lane). 48 blocks x 256 threads.
// ---------------------------------------------------------------------------
__global__ __launch_bounds__(256)
void wprep_kernel(const float* __restrict__ Wq, const float* __restrict__ Wk,
                  const float* __restrict__ Wv, u16* __restrict__ wbf)
{
    const int zkt = blockIdx.x;           // 0..47
    const int z   = zkt >> 4;
    const int kt  = zkt & 15;
    const float* W = (z == 0) ? Wq : (z == 1) ? Wk : Wv;
    const int kn   = threadIdx.x >> 6;
    const int lane = threadIdx.x & 63;
    const int l15  = lane & 15;
    const int lg   = lane >> 4;

    const float* src = W + (size_t)(kn * 16 + l15) * EMB + kt * 32 + lg * 8;
    f32x4_t f0 = *reinterpret_cast<const f32x4_t*>(src);
    f32x4_t f1 = *reinterpret_cast<const f32x4_t*>(src + 4);
    u16 tmp[8];
    #pragma unroll
    for (int e = 0; e < 4; ++e) { tmp[e] = to_bf(f0[e]); tmp[4 + e] = to_bf(f1[e]); }
    *reinterpret_cast<i32x4_t*>(
        &wbf[((size_t)((z * 16 + kt) * 4 + kn)) * 512 + lane * 8]) =
        *reinterpret_cast<const i32x4_t*>(tmp);
}

// ---------------------------------------------------------------------------
// Projection v4: LDS-FREE streaming MFMA. Each wave owns 16 rows and streams
// the full K=512 in 16 steps of 32, with an explicit depth-4 register
// pipeline (rolling buffers indexed by kt&3 -> compile-time after unroll).
// Per step: 2 A-loads (f32x4, 64B/row segments) + 4 W-frag loads (bf16x8,
// frag-ordered from wprep, 16B/lane coalesced, L2-hot). ~18-24 loads in
// flight per wave x 12 waves/CU -> the MLP a 5 TB/s stream needs.
// No LDS, no barriers. z: 0 -> Q, 1 -> K, 2 -> V (transposed [B][64][S]).
// ---------------------------------------------------------------------------
__global__ __launch_bounds__(256, 3)
void proj_kernel(const float* __restrict__ q_in, const float* __restrict__ k_in,
                 const float* __restrict__ v_in, const u16* __restrict__ wbf,
                 const float* __restrict__ bq, const float* __restrict__ bk,
                 const float* __restrict__ bv,
                 u16* __restrict__ outQ, u16* __restrict__ outK,
                 u16* __restrict__ outVT)
{
    const int z = blockIdx.y;
    const float* in   = (z == 0) ? q_in : (z == 1) ? k_in : v_in;
    const float* bias = (z == 0) ? bq   : (z == 1) ? bk   : bv;

    const int tid  = threadIdx.x;
    const int lane = tid & 63;
    const int w    = tid >> 6;
    const int l15  = lane & 15;
    const int lg   = lane >> 4;
    const int g0   = blockIdx.x * 64;
    const int row  = g0 + w * 16 + l15;

    const float* arow = in + (size_t)row * EMB + lg * 8;
    const u16*   wz   = wbf + (size_t)z * 16 * 4 * 512 + lane * 8;

    float bvals[4];
    #pragma unroll
    for (int kn = 0; kn < 4; ++kn) bvals[kn] = bias[kn * 16 + l15];
    asm volatile("" :: "v"(bvals[0]), "v"(bvals[1]), "v"(bvals[2]), "v"(bvals[3]));

    f32x4_t acc[4];
    #pragma unroll
    for (int i = 0; i < 4; ++i)
        #pragma unroll
        for (int j = 0; j < 4; ++j) acc[i][j] = 0.f;

    // rolling depth-4 pipeline buffers (all indices literal after unroll)
    f32x4_t  a0[4], a1[4];
    bf16x8_t wf[4][4];

#define ISSUE(kt)                                                              \
    {                                                                          \
        a0[(kt) & 3] = *reinterpret_cast<const f32x4_t*>(arow + (kt) * 32);    \
        a1[(kt) & 3] = *reinterpret_cast<const f32x4_t*>(arow + (kt) * 32 + 4);\
        _Pragma("unroll")                                                      \
        for (int kn = 0; kn < 4; ++kn)                                         \
            wf[(kt) & 3][kn] = *reinterpret_cast<const bf16x8_t*>(             \
                wz + ((size_t)((kt) * 4 + kn) << 9));                          \
    }

    // prologue: fill 4 slots (24 loads in flight)
    #pragma unroll
    for (int kt = 0; kt < 4; ++kt) ISSUE(kt);

    #pragma unroll
    for (int kt = 0; kt < 16; ++kt) {
        const int s = kt & 3;
        // consume slot s
        u16 ta[8];
        #pragma unroll
        for (int e = 0; e < 4; ++e) { ta[e] = to_bf(a0[s][e]); ta[4 + e] = to_bf(a1[s][e]); }
        bf16x8_t af = *reinterpret_cast<const bf16x8_t*>(ta);
        #pragma unroll
        for (int kn = 0; kn < 4; ++kn)
            acc[kn] = __builtin_amdgcn_mfma_f32_16x16x32_bf16(af, wf[s][kn], acc[kn], 0, 0, 0);
        // refill slot s with step kt+4
        if (kt < 12) ISSUE(kt + 4);
    }
#undef ISSUE

    // epilogue: bias add, bf16 store
    #pragma unroll
    for (int kn = 0; kn < 4; ++kn) {
        const int col = kn * 16 + l15;
        #pragma unroll
        for (int j = 0; j < 4; ++j) {
            const int grow = g0 + w * 16 + lg * 4 + j;
            const u16 val = to_bf(acc[kn][j] + bvals[kn]);
            if (z == 0) {
                outQ[(size_t)grow * HD + col] = val;
            } else if (z == 1) {
                outK[(size_t)grow * HD + col] = val;
            } else {
                const int b = grow >> 12, s2 = grow & (SEQ - 1);
                outVT[((size_t)(b * HD + col)) * SEQ + s2] = val;
            }
        }
    }
}

// ---------------------------------------------------------------------------
// 8-wave flash attention (m214-style), split-K partials. (unchanged from R5)
// ---------------------------------------------------------------------------
__global__ __launch_bounds__(512, 4)
void attn8_kernel(const u16* __restrict__ Q, const u16* __restrict__ K,
                  const u16* __restrict__ VT,
                  u16* __restrict__ partO, float* __restrict__ partL)
{
    __shared__ u16 Kt[2][64 * 64];   // [buf][key*64 + h], chunk-swizzled
    __shared__ u16 Vt[2][64 * 64];   // [buf][d*64 + key], chunk-swizzled
    __shared__ u16 Pt[8][32 * 64];   // per-wave P^T [q][key], swizzled

    const int tid  = threadIdx.x;
    const int w    = tid >> 6;
    const int lane = tid & 63;
    const int q31  = lane & 31;
    const int half = lane >> 5;

    const int b = blockIdx.y;
    const int y = blockIdx.x;                 // 0..135
    int g = 0;
    while ((g + 1) * (g + 2) / 2 <= y) ++g;
    const int c = y - g * (g + 1) / 2;        // chunk 0..g

    const int R0   = 256 * g + 32 * w;        // wave's first q row
    const int q_g  = R0 + q31;                // this lane's q row
    const int nt_w = 4 * g + (w >> 1) + 1;    // key tiles this wave needs
    const int t0   = 4 * c, t1 = 4 * c + 4;   // block-wide staged tile range

    const u16* Kb  = K  + (size_t)b * SEQ * HD;
    const u16* VTb = VT + (size_t)b * HD * SEQ;

    const int srow = w * 8 + (lane >> 3);            // row within 64-row tile
    const int schk = (lane & 7) ^ ((lane >> 3) & 7); // pre-swizzled src chunk

    bf16x8_t qf0, qf1, qf2, qf3;
    {
        const u16* qp = Q + ((size_t)b * SEQ + q_g) * HD + 8 * half;
        qf0 = *(const bf16x8_t*)(qp + 0);
        qf1 = *(const bf16x8_t*)(qp + 16);
        qf2 = *(const bf16x8_t*)(qp + 32);
        qf3 = *(const bf16x8_t*)(qp + 48);
    }

    f32x16_t acc0, acc1;
    #pragma unroll
    for (int i = 0; i < 16; ++i) { acc0[i] = 0.f; acc1[i] = 0.f; }
    float lsum = 0.f;

    auto STAGE = [&](int u, int t) {
        stage16(&Kb[((size_t)(t * 64 + srow)) * HD + schk * 8], &Kt[u][w * 512]);
        stage16(&VTb[(size_t)srow * SEQ + t * 64 + schk * 8],   &Vt[u][w * 512]);
    };

    STAGE(0, t0);
    asm volatile("s_waitcnt vmcnt(0)" ::: "memory");
    __syncthreads();

    for (int t = t0; t < t1; ++t) {
        const int u = (t - t0) & 1;
        if (t + 1 < t1) STAGE(u ^ 1, t + 1);
        if (t < nt_w) {
            const bool last = (t == nt_w - 1);
            #pragma unroll
            for (int ksub = 0; ksub < 2; ++ksub) {
                f32x16_t sf;
                #pragma unroll
                for (int i = 0; i < 16; ++i) sf[i] = 0.f;
                const int kl = ksub * 32 + q31;
                #pragma unroll
                for (int s = 0; s < 4; ++s) {
                    bf16x8_t a = *(const bf16x8_t*)
                        &Kt[u][kl * 64 + ((s * 16 + 8 * half) ^ ((kl & 7) << 3))];
                    bf16x8_t qq = (s == 0) ? qf0 : (s == 1) ? qf1 : (s == 2) ? qf2 : qf3;
                    sf = __builtin_amdgcn_mfma_f32_32x32x16_bf16(a, qq, sf, 0, 0, 0);
                }
                #pragma unroll
                for (int j = 0; j < 4; ++j) {
                    float p[4];
                    #pragma unroll
                    for (int e = 0; e < 4; ++e) {
                        const int kk    = 8 * j + 4 * half + e;
                        const int key_g = t * 64 + ksub * 32 + kk;
                        float v = exp2f(sf[4 * j + e] * C2);
                        if (last && key_g > q_g) v = 0.f;
                        lsum += v;
                        p[e] = v;
                    }
                    u32x2_t pk;
                    pk[0] = (u32)to_bf(p[0]) | ((u32)to_bf(p[1]) << 16);
                    pk[1] = (u32)to_bf(p[2]) | ((u32)to_bf(p[3]) << 16);
                    const int col = (ksub * 32 + 8 * j + 4 * half) ^ ((q31 & 7) << 3);
                    *(u32x2_t*)&Pt[w][q31 * 64 + col] = pk;
                }
            }
            asm volatile("s_waitcnt lgkmcnt(0)" ::: "memory");
            __builtin_amdgcn_sched_barrier(0);
            #pragma unroll
            for (int kp = 0; kp < 4; ++kp) {
                bf16x8_t pb = *(const bf16x8_t*)
                    &Pt[w][q31 * 64 + ((kp * 16 + 8 * half) ^ ((q31 & 7) << 3))];
                {
                    const int dl = q31;
                    bf16x8_t va = *(const bf16x8_t*)
                        &Vt[u][dl * 64 + ((kp * 16 + 8 * half) ^ ((dl & 7) << 3))];
                    acc0 = __builtin_amdgcn_mfma_f32_32x32x16_bf16(va, pb, acc0, 0, 0, 0);
                }
                {
                    const int dl = 32 + q31;
                    bf16x8_t va = *(const bf16x8_t*)
                        &Vt[u][dl * 64 + ((kp * 16 + 8 * half) ^ ((dl & 7) << 3))];
                    acc1 = __builtin_amdgcn_mfma_f32_32x32x16_bf16(va, pb, acc1, 0, 0, 0);
                }
            }
        }
        asm volatile("s_waitcnt vmcnt(0)" ::: "memory");
        __syncthreads();
    }

    lsum += __shfl_xor(lsum, 32);
    const int slot = (b * NPAIR + y) * 8 + w;
    u16* po = partO + (size_t)slot * 2048;
    #pragma unroll
    for (int dsub = 0; dsub < 2; ++dsub) {
        #pragma unroll
        for (int j = 0; j < 4; ++j) {
            const f32x16_t& a = dsub ? acc1 : acc0;
            u32x2_t pk;
            pk[0] = (u32)to_bf(a[4 * j + 0]) | ((u32)to_bf(a[4 * j + 1]) << 16);
            pk[1] = (u32)to_bf(a[4 * j + 2]) | ((u32)to_bf(a[4 * j + 3]) << 16);
            const int d = 32 * dsub + 8 * j + 4 * half;
            *(u32x2_t*)&po[q31 * 64 + d] = pk;
        }
    }
    if (half == 0) partL[(size_t)slot * 32 + q31] = lsum;
}

// ---------------------------------------------------------------------------
// Reduce: sum bf16 O partials + lsum over chunks, divide, write f32 out.
// ---------------------------------------------------------------------------
__global__ __launch_bounds__(256)
void reduce8_kernel(const u16* __restrict__ partO, const float* __restrict__ partL,
                    float* __restrict__ out)
{
    const int x  = blockIdx.x;          // 0..511
    const int b  = x >> 7;
    const int gw = x & 127;
    const int g  = gw >> 3;
    const int w  = gw & 7;
    const int ybase = g * (g + 1) / 2;

    const int t  = threadIdx.x;
    const int q  = t >> 3;              // 0..31
    const int d0 = (t & 7) * 8;         // 0,8,..,56

    float acc[8];
    #pragma unroll
    for (int i = 0; i < 8; ++i) acc[i] = 0.f;
    float l = 0.f;

    for (int c = 0; c <= g; ++c) {
        const int slot = (b * NPAIR + ybase + c) * 8 + w;
        i32x4_t raw = *(const i32x4_t*)(partO + (size_t)slot * 2048 + q * 64 + d0);
        const u16* pr = (const u16*)&raw;
        #pragma unroll
        for (int i = 0; i < 8; ++i) {
            u32 bits = ((u32)pr[i]) << 16;
            acc[i] += __builtin_bit_cast(float, bits);
        }
        l += partL[(size_t)slot * 32 + q];
    }
    const float inv = 1.f / l;
    f32x4_t r0, r1;
    #pragma unroll
    for (int i = 0; i < 4; ++i) { r0[i] = acc[i] * inv; r1[i] = acc[4 + i] * inv; }
    const size_t row = (size_t)b * SEQ + g * 256 + w * 32 + q;
    *(f32x4_t*)&out[row * HD + d0]     = r0;
    *(f32x4_t*)&out[row * HD + d0 + 4] = r1;
}

extern "C" void kernel_launch(void* const* d_in, const int* in_sizes, int n_in,
                              void* d_out, int out_size, void* d_ws, size_t ws_size,
                              hipStream_t stream)
{
    const float* q_in = (const float*)d_in[0];
    const float* k_in = (const float*)d_in[1];
    const float* v_in = (const float*)d_in[2];
    const float* Wq   = (const float*)d_in[3];
    const float* bq   = (const float*)d_in[4];
    const float* Wk   = (const float*)d_in[5];
    const float* bk   = (const float*)d_in[6];
    const float* Wv   = (const float*)d_in[7];
    const float* bv   = (const float*)d_in[8];
    float* out = (float*)d_out;

    const size_t NQ = (size_t)NBATCH * SEQ * HD;     // 1,048,576 elems
    u16* wsQ   = (u16*)d_ws;
    u16* wsK   = wsQ + NQ;
    u16* wsVT  = wsK + NQ;
    u16* partO = wsVT + NQ;                          // SLOTS*2048 u16 = 17.8 MB
    float* partL = (float*)(partO + (size_t)SLOTS * 2048);  // SLOTS*32 f32
    // wbf aliases the head of partO: consumed by proj BEFORE attn8 writes partO
    u16* wbf = partO;                                // 3*16*4*512 u16 = 192 KB

    wprep_kernel<<<dim3(48), 256, 0, stream>>>(Wq, Wk, Wv, wbf);
    proj_kernel<<<dim3(256, 3), 256, 0, stream>>>(q_in, k_in, v_in, wbf,
                                                  bq, bk, bv, wsQ, wsK, wsVT);
    attn8_kernel<<<dim3(NPAIR, NBATCH), 512, 0, stream>>>(wsQ, wsK, wsVT, partO, partL);
    reduce8_kernel<<<dim3(512), 256, 0, stream>>>(partO, partL, out);
}

// Round 10
// 70.666 us; speedup vs baseline: 1.1166x; 1.0196x over previous
//
#include <hip/hip_runtime.h>
#include <hip/hip_bf16.h>
#include <math.h>

typedef unsigned short u16;
typedef unsigned int   u32;
typedef __attribute__((ext_vector_type(8)))  short bf16x8_t;
typedef __attribute__((ext_vector_type(4)))  float f32x4_t;
typedef __attribute__((ext_vector_type(16))) float f32x16_t;
typedef __attribute__((ext_vector_type(4)))  int   i32x4_t;
typedef __attribute__((ext_vector_type(2)))  u32   u32x2_t;

#define SEQ 4096
#define EMB 512
#define HD  64
#define NBATCH 4
// 1/sqrt(512) * log2(e)  (bug-faithful d_k = embed dim 512)
#define C2 0.063758718f

#define NPAIR 136                    // (g,c) pairs per batch: sum_{g=0..15}(g+1)
#define SLOTS (NBATCH * NPAIR * 8)   // 4352 wave-partial slots

__device__ __forceinline__ u16 to_bf(float f) {
    __hip_bfloat16 h = __float2bfloat16(f);
    return __builtin_bit_cast(u16, h);
}

__device__ __forceinline__ void stage16(const void* g, void* l) {
    __builtin_amdgcn_global_load_lds(
        (const __attribute__((address_space(1))) void*)g,
        (__attribute__((address_space(3))) void*)l, 16, 0, 0);
}

// ---------------------------------------------------------------------------
// W prep: convert W (f32 [64][512]) to bf16 in MFMA-B-fragment order.
// wbf[((z*16+kt)*4+kn)*512 + lane*8 + e] = W_z[kn*16+(lane&15)][kt*32+(lane>>4)*8+e]
// ---------------------------------------------------------------------------
__global__ __launch_bounds__(256)
void wprep_kernel(const float* __restrict__ Wq, const float* __restrict__ Wk,
                  const float* __restrict__ Wv, u16* __restrict__ wbf)
{
    const int zkt = blockIdx.x;           // 0..47
    const int z   = zkt >> 4;
    const int kt  = zkt & 15;
    const float* W = (z == 0) ? Wq : (z == 1) ? Wk : Wv;
    const int kn   = threadIdx.x >> 6;
    const int lane = threadIdx.x & 63;
    const int l15  = lane & 15;
    const int lg   = lane >> 4;

    const float* src = W + (size_t)(kn * 16 + l15) * EMB + kt * 32 + lg * 8;
    f32x4_t f0 = *reinterpret_cast<const f32x4_t*>(src);
    f32x4_t f1 = *reinterpret_cast<const f32x4_t*>(src + 4);
    u16 tmp[8];
    #pragma unroll
    for (int e = 0; e < 4; ++e) { tmp[e] = to_bf(f0[e]); tmp[4 + e] = to_bf(f1[e]); }
    *reinterpret_cast<i32x4_t*>(
        &wbf[((size_t)((z * 16 + kt) * 4 + kn)) * 512 + lane * 8]) =
        *reinterpret_cast<const i32x4_t*>(tmp);
}

// ---------------------------------------------------------------------------
// Projection v6: async-DMA A-stream, race-free ordering.
// Wave-private LDS ring (4 slots x 16 rows x 32 f32 = 32 KB/block) filled by
// global_load_lds. Per iteration: wait vmcnt(6) -> ds_read slot -> MFMA ->
// ISSUE(kt+4) into the SAME slot (safe: WAR in program order; the MFMA's
// lgkmcnt dependency forces the ds_read to complete before the DMA issues).
// R9 BUG: issuing kt+4 BEFORE the consume raced the DMA against the ds_read
// of the same ring slot (depth 4, distance 4 == 0 mod 4) -> absmax 0.617.
// Zero barriers in the whole kernel; A chunks XOR-swizzled src-side.
// z: 0 -> Q, 1 -> K, 2 -> V (transposed [B][64][S]).
// ---------------------------------------------------------------------------
__global__ __launch_bounds__(256)
void proj_kernel(const float* __restrict__ q_in, const float* __restrict__ k_in,
                 const float* __restrict__ v_in, const u16* __restrict__ wbf,
                 const float* __restrict__ bq, const float* __restrict__ bk,
                 const float* __restrict__ bv,
                 u16* __restrict__ outQ, u16* __restrict__ outK,
                 u16* __restrict__ outVT)
{
    const int z = blockIdx.y;
    const float* in   = (z == 0) ? q_in : (z == 1) ? k_in : v_in;
    const float* bias = (z == 0) ? bq   : (z == 1) ? bk   : bv;

    __shared__ __align__(16) float A_lds[4][4][16][32];   // [slot][wave][row][chunk-swz]

    const int tid  = threadIdx.x;
    const int lane = tid & 63;
    const int w    = tid >> 6;
    const int l15  = lane & 15;
    const int lg   = lane >> 4;
    const int g0   = blockIdx.x * 64;

    const u16* wz = wbf + (size_t)z * 16 * 4 * 512 + lane * 8;

    float bvals[4];
    #pragma unroll
    for (int kn = 0; kn < 4; ++kn) bvals[kn] = bias[kn * 16 + l15];
    asm volatile("" :: "v"(bvals[0]), "v"(bvals[1]), "v"(bvals[2]), "v"(bvals[3]));

    // staging geometry (per instr i=0,1): lane covers row i*8 + (lane>>3),
    // LDS chunk lane&7; source chunk = (lane&7) ^ (row&7)  (involution)
    const int sr = lane >> 3;                        // 0..7
    const int sc = (lane & 7) ^ (sr & 7);            // pre-swizzled src chunk
    const float* abase = in + (size_t)(g0 + w * 16 + sr) * EMB + sc * 4;

#define ISSUE(kt)                                                               \
    {                                                                           \
        stage16(abase +            (kt) * 32, &A_lds[(kt) & 3][w][0][0]);       \
        stage16(abase + 8 * EMB +  (kt) * 32, &A_lds[(kt) & 3][w][8][0]);       \
    }

    f32x4_t acc[4];
    #pragma unroll
    for (int i = 0; i < 4; ++i)
        #pragma unroll
        for (int j = 0; j < 4; ++j) acc[i][j] = 0.f;

    const int rsw = l15 & 7;
    const int p0  = (lg * 2) ^ rsw;                  // swizzled read position

    ISSUE(0); ISSUE(1); ISSUE(2); ISSUE(3);

    #pragma unroll
    for (int kt = 0; kt < 16; ++kt) {
        // wait until tile kt's 2 DMA instrs have landed (outstanding = tiles
        // kt..kt+3 = 8 instrs at steady state -> drain to 6)
        if (kt <= 12)      asm volatile("s_waitcnt vmcnt(6)" ::: "memory");
        else if (kt == 13) asm volatile("s_waitcnt vmcnt(4)" ::: "memory");
        else if (kt == 14) asm volatile("s_waitcnt vmcnt(2)" ::: "memory");
        else               asm volatile("s_waitcnt vmcnt(0)" ::: "memory");
        __builtin_amdgcn_sched_barrier(0);

        const int s = kt & 3;
        f32x4_t a0 = *reinterpret_cast<const f32x4_t*>(&A_lds[s][w][l15][p0 * 4]);
        f32x4_t a1 = *reinterpret_cast<const f32x4_t*>(&A_lds[s][w][l15][(p0 ^ 1) * 4]);
        u16 ta[8];
        #pragma unroll
        for (int e = 0; e < 4; ++e) { ta[e] = to_bf(a0[e]); ta[4 + e] = to_bf(a1[e]); }
        bf16x8_t af = *reinterpret_cast<const bf16x8_t*>(ta);
        #pragma unroll
        for (int kn = 0; kn < 4; ++kn) {
            bf16x8_t wfrag = *reinterpret_cast<const bf16x8_t*>(
                wz + ((size_t)(kt * 4 + kn) << 9));
            acc[kn] = __builtin_amdgcn_mfma_f32_16x16x32_bf16(af, wfrag, acc[kn], 0, 0, 0);
        }
        // refill slot s AFTER its data has been consumed (WAR-safe)
        if (kt < 12) ISSUE(kt + 4);
    }
#undef ISSUE

    // epilogue: bias add, bf16 store
    #pragma unroll
    for (int kn = 0; kn < 4; ++kn) {
        const int col = kn * 16 + l15;
        #pragma unroll
        for (int j = 0; j < 4; ++j) {
            const int grow = g0 + w * 16 + lg * 4 + j;
            const u16 val = to_bf(acc[kn][j] + bvals[kn]);
            if (z == 0) {
                outQ[(size_t)grow * HD + col] = val;
            } else if (z == 1) {
                outK[(size_t)grow * HD + col] = val;
            } else {
                const int b = grow >> 12, s2 = grow & (SEQ - 1);
                outVT[((size_t)(b * HD + col)) * SEQ + s2] = val;
            }
        }
    }
}

// ---------------------------------------------------------------------------
// 8-wave flash attention (m214-style), split-K partials. (unchanged from R5)
// ---------------------------------------------------------------------------
__global__ __launch_bounds__(512, 4)
void attn8_kernel(const u16* __restrict__ Q, const u16* __restrict__ K,
                  const u16* __restrict__ VT,
                  u16* __restrict__ partO, float* __restrict__ partL)
{
    __shared__ u16 Kt[2][64 * 64];   // [buf][key*64 + h], chunk-swizzled
    __shared__ u16 Vt[2][64 * 64];   // [buf][d*64 + key], chunk-swizzled
    __shared__ u16 Pt[8][32 * 64];   // per-wave P^T [q][key], swizzled

    const int tid  = threadIdx.x;
    const int w    = tid >> 6;
    const int lane = tid & 63;
    const int q31  = lane & 31;
    const int half = lane >> 5;

    const int b = blockIdx.y;
    const int y = blockIdx.x;                 // 0..135
    int g = 0;
    while ((g + 1) * (g + 2) / 2 <= y) ++g;
    const int c = y - g * (g + 1) / 2;        // chunk 0..g

    const int R0   = 256 * g + 32 * w;        // wave's first q row
    const int q_g  = R0 + q31;                // this lane's q row
    const int nt_w = 4 * g + (w >> 1) + 1;    // key tiles this wave needs
    const int t0   = 4 * c, t1 = 4 * c + 4;   // block-wide staged tile range

    const u16* Kb  = K  + (size_t)b * SEQ * HD;
    const u16* VTb = VT + (size_t)b * HD * SEQ;

    const int srow = w * 8 + (lane >> 3);            // row within 64-row tile
    const int schk = (lane & 7) ^ ((lane >> 3) & 7); // pre-swizzled src chunk

    bf16x8_t qf0, qf1, qf2, qf3;
    {
        const u16* qp = Q + ((size_t)b * SEQ + q_g) * HD + 8 * half;
        qf0 = *(const bf16x8_t*)(qp + 0);
        qf1 = *(const bf16x8_t*)(qp + 16);
        qf2 = *(const bf16x8_t*)(qp + 32);
        qf3 = *(const bf16x8_t*)(qp + 48);
    }

    f32x16_t acc0, acc1;
    #pragma unroll
    for (int i = 0; i < 16; ++i) { acc0[i] = 0.f; acc1[i] = 0.f; }
    float lsum = 0.f;

    auto STAGE = [&](int u, int t) {
        stage16(&Kb[((size_t)(t * 64 + srow)) * HD + schk * 8], &Kt[u][w * 512]);
        stage16(&VTb[(size_t)srow * SEQ + t * 64 + schk * 8],   &Vt[u][w * 512]);
    };

    STAGE(0, t0);
    asm volatile("s_waitcnt vmcnt(0)" ::: "memory");
    __syncthreads();

    for (int t = t0; t < t1; ++t) {
        const int u = (t - t0) & 1;
        if (t + 1 < t1) STAGE(u ^ 1, t + 1);
        if (t < nt_w) {
            const bool last = (t == nt_w - 1);
            #pragma unroll
            for (int ksub = 0; ksub < 2; ++ksub) {
                f32x16_t sf;
                #pragma unroll
                for (int i = 0; i < 16; ++i) sf[i] = 0.f;
                const int kl = ksub * 32 + q31;
                #pragma unroll
                for (int s = 0; s < 4; ++s) {
                    bf16x8_t a = *(const bf16x8_t*)
                        &Kt[u][kl * 64 + ((s * 16 + 8 * half) ^ ((kl & 7) << 3))];
                    bf16x8_t qq = (s == 0) ? qf0 : (s == 1) ? qf1 : (s == 2) ? qf2 : qf3;
                    sf = __builtin_amdgcn_mfma_f32_32x32x16_bf16(a, qq, sf, 0, 0, 0);
                }
                #pragma unroll
                for (int j = 0; j < 4; ++j) {
                    float p[4];
                    #pragma unroll
                    for (int e = 0; e < 4; ++e) {
                        const int kk    = 8 * j + 4 * half + e;
                        const int key_g = t * 64 + ksub * 32 + kk;
                        float v = exp2f(sf[4 * j + e] * C2);
                        if (last && key_g > q_g) v = 0.f;
                        lsum += v;
                        p[e] = v;
                    }
                    u32x2_t pk;
                    pk[0] = (u32)to_bf(p[0]) | ((u32)to_bf(p[1]) << 16);
                    pk[1] = (u32)to_bf(p[2]) | ((u32)to_bf(p[3]) << 16);
                    const int col = (ksub * 32 + 8 * j + 4 * half) ^ ((q31 & 7) << 3);
                    *(u32x2_t*)&Pt[w][q31 * 64 + col] = pk;
                }
            }
            asm volatile("s_waitcnt lgkmcnt(0)" ::: "memory");
            __builtin_amdgcn_sched_barrier(0);
            #pragma unroll
            for (int kp = 0; kp < 4; ++kp) {
                bf16x8_t pb = *(const bf16x8_t*)
                    &Pt[w][q31 * 64 + ((kp * 16 + 8 * half) ^ ((q31 & 7) << 3))];
                {
                    const int dl = q31;
                    bf16x8_t va = *(const bf16x8_t*)
                        &Vt[u][dl * 64 + ((kp * 16 + 8 * half) ^ ((dl & 7) << 3))];
                    acc0 = __builtin_amdgcn_mfma_f32_32x32x16_bf16(va, pb, acc0, 0, 0, 0);
                }
                {
                    const int dl = 32 + q31;
                    bf16x8_t va = *(const bf16x8_t*)
                        &Vt[u][dl * 64 + ((kp * 16 + 8 * half) ^ ((dl & 7) << 3))];
                    acc1 = __builtin_amdgcn_mfma_f32_32x32x16_bf16(va, pb, acc1, 0, 0, 0);
                }
            }
        }
        asm volatile("s_waitcnt vmcnt(0)" ::: "memory");
        __syncthreads();
    }

    lsum += __shfl_xor(lsum, 32);
    const int slot = (b * NPAIR + y) * 8 + w;
    u16* po = partO + (size_t)slot * 2048;
    #pragma unroll
    for (int dsub = 0; dsub < 2; ++dsub) {
        #pragma unroll
        for (int j = 0; j < 4; ++j) {
            const f32x16_t& a = dsub ? acc1 : acc0;
            u32x2_t pk;
            pk[0] = (u32)to_bf(a[4 * j + 0]) | ((u32)to_bf(a[4 * j + 1]) << 16);
            pk[1] = (u32)to_bf(a[4 * j + 2]) | ((u32)to_bf(a[4 * j + 3]) << 16);
            const int d = 32 * dsub + 8 * j + 4 * half;
            *(u32x2_t*)&po[q31 * 64 + d] = pk;
        }
    }
    if (half == 0) partL[(size_t)slot * 32 + q31] = lsum;
}

// ---------------------------------------------------------------------------
// Reduce: sum bf16 O partials + lsum over chunks, divide, write f32 out.
// ---------------------------------------------------------------------------
__global__ __launch_bounds__(256)
void reduce8_kernel(const u16* __restrict__ partO, const float* __restrict__ partL,
                    float* __restrict__ out)
{
    const int x  = blockIdx.x;          // 0..511
    const int b  = x >> 7;
    const int gw = x & 127;
    const int g  = gw >> 3;
    const int w  = gw & 7;
    const int ybase = g * (g + 1) / 2;

    const int t  = threadIdx.x;
    const int q  = t >> 3;              // 0..31
    const int d0 = (t & 7) * 8;         // 0,8,..,56

    float acc[8];
    #pragma unroll
    for (int i = 0; i < 8; ++i) acc[i] = 0.f;
    float l = 0.f;

    for (int c = 0; c <= g; ++c) {
        const int slot = (b * NPAIR + ybase + c) * 8 + w;
        i32x4_t raw = *(const i32x4_t*)(partO + (size_t)slot * 2048 + q * 64 + d0);
        const u16* pr = (const u16*)&raw;
        #pragma unroll
        for (int i = 0; i < 8; ++i) {
            u32 bits = ((u32)pr[i]) << 16;
            acc[i] += __builtin_bit_cast(float, bits);
        }
        l += partL[(size_t)slot * 32 + q];
    }
    const float inv = 1.f / l;
    f32x4_t r0, r1;
    #pragma unroll
    for (int i = 0; i < 4; ++i) { r0[i] = acc[i] * inv; r1[i] = acc[4 + i] * inv; }
    const size_t row = (size_t)b * SEQ + g * 256 + w * 32 + q;
    *(f32x4_t*)&out[row * HD + d0]     = r0;
    *(f32x4_t*)&out[row * HD + d0 + 4] = r1;
}

extern "C" void kernel_launch(void* const* d_in, const int* in_sizes, int n_in,
                              void* d_out, int out_size, void* d_ws, size_t ws_size,
                              hipStream_t stream)
{
    const float* q_in = (const float*)d_in[0];
    const float* k_in = (const float*)d_in[1];
    const float* v_in = (const float*)d_in[2];
    const float* Wq   = (const float*)d_in[3];
    const float* bq   = (const float*)d_in[4];
    const float* Wk   = (const float*)d_in[5];
    const float* bk   = (const float*)d_in[6];
    const float* Wv   = (const float*)d_in[7];
    const float* bv   = (const float*)d_in[8];
    float* out = (float*)d_out;

    const size_t NQ = (size_t)NBATCH * SEQ * HD;     // 1,048,576 elems
    u16* wsQ   = (u16*)d_ws;
    u16* wsK   = wsQ + NQ;
    u16* wsVT  = wsK + NQ;
    u16* partO = wsVT + NQ;                          // SLOTS*2048 u16 = 17.8 MB
    float* partL = (float*)(partO + (size_t)SLOTS * 2048);  // SLOTS*32 f32
    // wbf aliases the head of partO: consumed by proj BEFORE attn8 writes partO
    u16* wbf = partO;                                // 3*16*4*512 u16 = 192 KB

    wprep_kernel<<<dim3(48), 256, 0, stream>>>(Wq, Wk, Wv, wbf);
    proj_kernel<<<dim3(256, 3), 256, 0, stream>>>(q_in, k_in, v_in, wbf,
                                                  bq, bk, bv, wsQ, wsK, wsVT);
    attn8_kernel<<<dim3(NPAIR, NBATCH), 512, 0, stream>>>(wsQ, wsK, wsVT, partO, partL);
    reduce8_kernel<<<dim3(512), 256, 0, stream>>>(partO, partL, out);
}